// Round 4
// baseline (246.844 us; speedup 1.0000x reference)
//
#include <hip/hip_runtime.h>
#include <hip/hip_bf16.h>

typedef unsigned short u16;
typedef __attribute__((ext_vector_type(4))) short bf16x4;
typedef __attribute__((ext_vector_type(8))) short bf16x8;
typedef __attribute__((ext_vector_type(4))) float f32x4;
typedef __attribute__((ext_vector_type(16))) float f32x16;

#define NB_ 4
#define NT_ 2048
#define NC_ 768
#define NH_ 12
#define ND_ 64
#define NM_ (NB_*NT_)   // 8192 rows

// 1/sqrt(64) * log2(e): folded into q at the QKV epilogue -> attention runs in exp2 domain
#define SCQ_ 0.18033688011112042f

__device__ __forceinline__ u16 f2bf(float f){
  union { float f; unsigned u; } c; c.f = f;
  unsigned u = c.u;
  return (u16)((u + 0x7fffu + ((u>>16)&1u)) >> 16);  // RNE
}

__device__ __forceinline__ unsigned pkbf(float a, float b){
  __hip_bfloat162 h = __float22bfloat162_rn(make_float2(a,b));  // v_cvt_pk_bf16_f32
  union { __hip_bfloat162 h; unsigned u; } c; c.h = h; return c.u;
}

__device__ __forceinline__ bf16x8 cat4(bf16x4 lo, bf16x4 hi){
  return __builtin_shufflevector(lo, hi, 0,1,2,3,4,5,6,7);
}

__device__ __forceinline__ f32x4 mfma16(bf16x8 a, bf16x8 b, f32x4 c){
  return __builtin_amdgcn_mfma_f32_16x16x32_bf16(a, b, c, 0, 0, 0);
}
__device__ __forceinline__ f32x16 mfma32(bf16x8 a, bf16x8 b, f32x16 c){
  return __builtin_amdgcn_mfma_f32_32x32x16_bf16(a, b, c, 0, 0, 0);
}

__device__ __forceinline__ void gload_lds16(const void* g, void* l){
  __builtin_amdgcn_global_load_lds(
    (const __attribute__((address_space(1))) void*)g,
    (__attribute__((address_space(3))) void*)l, 16, 0, 0);
}

// ---------------- cast x (f32 -> bf16), 4 elems/thread ----------------
__global__ __launch_bounds__(256) void cast_f32_bf16_k(
    const float* __restrict__ in, u16* __restrict__ out, int n4){
  int i = blockIdx.x*256 + threadIdx.x;
  if (i >= n4) return;
  float4 v = ((const float4*)in)[i];
  bf16x4 o;
  o[0]=(short)f2bf(v.x); o[1]=(short)f2bf(v.y);
  o[2]=(short)f2bf(v.z); o[3]=(short)f2bf(v.w);
  ((bf16x4*)out)[i] = o;
}

// ------------- transpose + cast: in f32 [R][Cc] -> out bf16 [Cc][R] -------------
__global__ __launch_bounds__(256) void transpose_cast_k(
    const float* __restrict__ in, u16* __restrict__ out, int R, int Cc){
  __shared__ float tile[32][33];
  int tx = threadIdx.x, ty = threadIdx.y;          // 32 x 8
  int c0 = blockIdx.x*32, r0 = blockIdx.y*32;
  #pragma unroll
  for (int j=0;j<32;j+=8) tile[ty+j][tx] = in[(size_t)(r0+ty+j)*Cc + c0+tx];
  __syncthreads();
  #pragma unroll
  for (int j=0;j<32;j+=8) out[(size_t)(c0+ty+j)*R + r0+tx] = f2bf(tile[tx][ty+j]);
}

// ---------------- GEMM: C[128x128] = A[M,K] * BT[N,K]^T  (both bf16 row-major) -------
// MODE 0: qkv -> scatter bf16 to q*scale [B,H,T,D], k [B,H,T,D], v^T [B,H,D,T]
//         (v columns permuted within 16-blocks for attn's contiguous B-slot reads)
// MODE 1: proj -> f32 out [M][768] + bias
template<int MODE>
__global__ __launch_bounds__(256,2) void gemm128(
  const u16* __restrict__ A, const u16* __restrict__ BT, const float* __restrict__ bias,
  u16* __restrict__ qo, u16* __restrict__ ko, u16* __restrict__ vo,
  float* __restrict__ fo, int Ksz)
{
  __shared__ u16 lds[2][2][128*32];   // [buf][A/B][row*32], 64B rows, 32 KB total
  const int t = threadIdx.x, w = t>>6, l = t&63, g = l>>4, lr = l&15;
  const int brow = blockIdx.y*128, bcol = blockIdx.x*128;
  const int wr = (w>>1)*64, wc = (w&1)*64;

  f32x4 acc[4][4];
  #pragma unroll
  for (int i=0;i<4;i++)
    #pragma unroll
    for (int j=0;j<4;j++) acc[i][j] = (f32x4){0.f,0.f,0.f,0.f};

  auto stage = [&](int buf, int kt){
    #pragma unroll
    for (int it=0; it<2; ++it){
      int chunk = it*256 + t;           // 512 chunks per tile
      int r = chunk>>2;
      int sb = ((chunk&3)*16) ^ ((r&3)<<4);
      gload_lds16((const char*)(A  + (size_t)(brow+r)*Ksz + kt*32) + sb,
                  (char*)&lds[buf][0][0] + chunk*16);
      gload_lds16((const char*)(BT + (size_t)(bcol+r)*Ksz + kt*32) + sb,
                  (char*)&lds[buf][1][0] + chunk*16);
    }
  };

  auto ldfrag = [&](const u16* base, int row)->bf16x8{
    const char* rp = (const char*)(base + row*32);
    int sw = (row&3)<<4;
    bf16x4 lo = *(const bf16x4*)(rp + ((g*8) ^ sw));
    bf16x4 hi = *(const bf16x4*)(rp + ((32 + g*8) ^ sw));
    return cat4(lo,hi);
  };

  const int nk = Ksz/32;
  stage(0,0);
  __syncthreads();
  int cur = 0;
  for (int kt=0; kt<nk; ++kt){
    if (kt+1 < nk) stage(cur^1, kt+1);
    const u16* Ab = &lds[cur][0][0];
    const u16* Bb = &lds[cur][1][0];
    bf16x8 af[4], bfr[4];
    #pragma unroll
    for (int mi=0;mi<4;mi++) af[mi]  = ldfrag(Ab, wr + mi*16 + lr);
    #pragma unroll
    for (int nj=0;nj<4;nj++) bfr[nj] = ldfrag(Bb, wc + nj*16 + lr);
    #pragma unroll
    for (int mi=0;mi<4;mi++)
      #pragma unroll
      for (int nj=0;nj<4;nj++)
        acc[mi][nj] = mfma16(af[mi], bfr[nj], acc[mi][nj]);
    __syncthreads();
    cur ^= 1;
  }

  if (MODE == 1){
    #pragma unroll
    for (int nj=0;nj<4;nj++){
      int n = bcol + wc + nj*16 + lr;
      float bs = bias[n];
      #pragma unroll
      for (int mi=0;mi<4;mi++)
        #pragma unroll
        for (int r=0;r<4;r++){
          int m = brow + wr + mi*16 + g*4 + r;
          fo[(size_t)m*NC_ + n] = acc[mi][nj][r] + bs;
        }
    }
  } else {
    const int sec = bcol / NC_;                    // block-uniform (768 % 128 == 0)
    u16* outp = (sec==0) ? qo : (sec==1 ? ko : vo);
    #pragma unroll
    for (int nj=0;nj<4;nj++){
      int n = bcol + wc + nj*16 + lr;
      int cc = n - sec*NC_;
      int hd = cc >> 6, d = cc & 63;
      float bs = bias[n];
      #pragma unroll
      for (int mi=0;mi<4;mi++)
        #pragma unroll
        for (int r=0;r<4;r++){
          int m = brow + wr + mi*16 + g*4 + r;
          int bb = m >> 11, tt = m & 2047;
          float v = acc[mi][nj][r] + bs;
          if (sec == 0) v *= SCQ_;                 // pre-scale q for exp2-domain attn
          size_t off;
          if (sec == 2){
            // v^T [B,H,D,T], column permuted within 16-blocks: tt&15 == 4g+r
            int p = (tt & ~15) | r | ((g&2)<<1) | ((g&1)<<3);
            off = (((size_t)bb*NH_ + hd)*ND_ + d)*NT_ + p;
          } else {
            off = (((size_t)bb*NH_ + hd)*NT_ + tt)*ND_ + d;  // q,k [B,H,T,D]
          }
          outp[off] = f2bf(v);
        }
    }
  }
}

// ---------------- flash attention v3: no LDS, no barriers, L2-direct ----------------
// 4 independent waves/block, each owns 32 q rows. Swapped S^T = mfma(A=K, B=Q):
// softmax state lane-local (col=q=lane&31). QK uses pi-permuted contiguous 16B loads
// for BOTH operands (contraction-invariant); V stored column-permuted so PV's A-frag
// is a contiguous 16B load with natural slot map -> P feeds B-operand in-lane.
__global__ __launch_bounds__(256,3) void attn_kernel(
    const u16* __restrict__ qg, const u16* __restrict__ kg,
    const u16* __restrict__ vg, u16* __restrict__ y)
{
  const int t = threadIdx.x, w = t>>6, l = t&63;
  const int lq = l&31, h = l>>5;
  const int bid = blockIdx.x;
  const int qt = 15 - (bid/48);    // heaviest q-super-tiles first
  const int bh = bid % 48;
  const int bb = bh / NH_, hh = bh % NH_;
  const u16* qp = qg + (size_t)bh*NT_*ND_;
  const u16* kp = kg + (size_t)bh*NT_*ND_;
  const u16* vp = vg + (size_t)bh*ND_*NT_;
  const int qmin = qt*128 + w*32;
  const int q = qmin + lq;         // this lane's q row (column of S^T)

  // Q frags (pi-permuted): slot i of k-block ks holds Q[q][ks*16 + 8h + i]
  bf16x8 Qf[4];
  {
    const u16* qr = qp + (size_t)q*ND_ + 8*h;
    #pragma unroll
    for (int ks=0; ks<4; ++ks) Qf[ks] = *(const bf16x8*)(qr + ks*16);
  }

  // per-lane fragment base pointers (advance by chunk inside loop)
  const u16* kb0 = kp + (size_t)lq*ND_ + 8*h;        // K rows 0-31 of chunk
  const u16* kb1 = kb0 + 32*ND_;                     // K rows 32-63
  const u16* vb0 = vp + (size_t)lq*NT_ + 8*h;        // V^T rows (d) 0-31
  const u16* vb1 = vb0 + (size_t)32*NT_;             // V^T rows 32-63

  f32x16 o0, o1;                   // O^T acc: col=q, row d=(r&3)+8*(r>>2)+4h (+32 o1)
  #pragma unroll
  for (int r=0;r<16;r++){ o0[r]=0.f; o1[r]=0.f; }
  float mrun = -3e38f, lsum = 0.f;
  const int nc = 2*qt + (w>>1) + 1; // causal 64-kv chunks for this wave

  for (int c=0; c<nc; ++c){
    const int kv0 = c*64;

    // issue K then V fragment loads (V latency hides under QK+softmax)
    bf16x8 kf0[4], kf1[4], vf0[4], vf1[4];
    #pragma unroll
    for (int ks=0; ks<4; ++ks){
      kf0[ks] = *(const bf16x8*)(kb0 + (size_t)kv0*ND_ + ks*16);
      kf1[ks] = *(const bf16x8*)(kb1 + (size_t)kv0*ND_ + ks*16);
    }
    #pragma unroll
    for (int ks=0; ks<4; ++ks){
      vf0[ks] = *(const bf16x8*)(vb0 + kv0 + ks*16);
      vf1[ks] = *(const bf16x8*)(vb1 + kv0 + ks*16);
    }

    // S^T (64 kv x 32 q), q pre-scaled -> exp2 domain
    f32x16 s0, s1;
    #pragma unroll
    for (int r=0;r<16;r++){ s0[r]=0.f; s1[r]=0.f; }
    __builtin_amdgcn_s_setprio(1);
    #pragma unroll
    for (int ks=0; ks<4; ++ks){
      s0 = mfma32(kf0[ks], Qf[ks], s0);
      s1 = mfma32(kf1[ks], Qf[ks], s1);
    }
    __builtin_amdgcn_s_setprio(0);

    // causal mask: only the last (diagonal) chunk is partial; wave-uniform branch
    if (c == nc-1){
      #pragma unroll
      for (int r=0;r<16;r++){
        int kva = kv0 + (r&3) + 8*(r>>2) + 4*h;
        s0[r] = (kva      <= q) ? s0[r] : -3e38f;
        s1[r] = (kva + 32 <= q) ? s1[r] : -3e38f;
      }
    }

    // row max: pairwise tree (depth 5) + cross-half swap
    float mx[16];
    #pragma unroll
    for (int i=0;i<8;i++) mx[i]   = fmaxf(s0[2*i], s0[2*i+1]);
    #pragma unroll
    for (int i=0;i<8;i++) mx[8+i] = fmaxf(s1[2*i], s1[2*i+1]);
    #pragma unroll
    for (int st=8; st>=1; st>>=1)
      #pragma unroll
      for (int i=0;i<st;i++) mx[i] = fmaxf(mx[i], mx[i+st]);
    float m0 = fmaxf(mx[0], __shfl_xor(mx[0], 32));

    // defer-max (T13): rescale only when max grew past threshold
    if (__any(m0 > mrun + 8.f)){
      float mnew = fmaxf(mrun, m0);
      float fsc = exp2f(mrun - mnew);
      mrun = mnew;
      lsum *= fsc;
      #pragma unroll
      for (int r=0;r<16;r++){ o0[r]*=fsc; o1[r]*=fsc; }
    }

    // P = exp2(s - mrun); pack pairs; tree-sum partials
    float pp[16];
    union { unsigned wd[16]; bf16x8 v[4]; } pf;
    #pragma unroll
    for (int j=0;j<8;j++){
      float a = exp2f(s0[2*j] - mrun), b = exp2f(s0[2*j+1] - mrun);
      pp[j] = a + b;
      pf.wd[j] = pkbf(a,b);
    }
    #pragma unroll
    for (int j=0;j<8;j++){
      float a = exp2f(s1[2*j] - mrun), b = exp2f(s1[2*j+1] - mrun);
      pp[8+j] = a + b;
      pf.wd[8+j] = pkbf(a,b);
    }
    #pragma unroll
    for (int st=8; st>=1; st>>=1)
      #pragma unroll
      for (int i=0;i<st;i++) pp[i] += pp[i+st];
    lsum += pp[0] + __shfl_xor(pp[0], 32);

    // PV: O^T += V^T * P^T ; P regs feed B-operand directly (in-lane)
    __builtin_amdgcn_s_setprio(1);
    #pragma unroll
    for (int j=0;j<4;j++){
      o0 = mfma32(vf0[j], pf.v[j], o0);
      o1 = mfma32(vf1[j], pf.v[j], o1);
    }
    __builtin_amdgcn_s_setprio(0);
  }

  // epilogue: y[b][t=q][hh*64+d] = O^T[d][q] / lsum  (8B packed stores)
  float inv = 1.f / lsum;
  u16* yr = y + ((size_t)bb*NT_ + q)*NC_ + hh*ND_;
  #pragma unroll
  for (int db=0; db<2; ++db){
    #pragma unroll
    for (int g2=0; g2<4; ++g2){
      float e0 = (db ? o1[g2*4+0] : o0[g2*4+0]) * inv;
      float e1 = (db ? o1[g2*4+1] : o0[g2*4+1]) * inv;
      float e2 = (db ? o1[g2*4+2] : o0[g2*4+2]) * inv;
      float e3 = (db ? o1[g2*4+3] : o0[g2*4+3]) * inv;
      unsigned w0 = pkbf(e0,e1), w1 = pkbf(e2,e3);
      int d0 = db*32 + g2*8 + 4*h;
      *(uint2*)(yr + d0) = make_uint2(w0, w1);
    }
  }
}

// ---------------- launch ----------------
extern "C" void kernel_launch(void* const* d_in, const int* in_sizes, int n_in,
                              void* d_out, int out_size, void* d_ws, size_t ws_size,
                              hipStream_t stream) {
  const float* x  = (const float*)d_in[0];
  const float* wa = (const float*)d_in[1];
  const float* ba = (const float*)d_in[2];
  const float* wp = (const float*)d_in[3];
  const float* bp = (const float*)d_in[4];
  float* out = (float*)d_out;

  char* ws = (char*)d_ws;
  const size_t szXB = (size_t)NM_*NC_*2;        // 12,582,912
  const size_t szWA = (size_t)3*NC_*NC_*2;      //  3,538,944
  const size_t szWP = (size_t)NC_*NC_*2;        //  1,179,648
  const size_t szQ  = szXB;
  u16* xb  = (u16*)(ws);
  u16* wat = (u16*)(ws + szXB);
  u16* wpt = (u16*)(ws + szXB + szWA);
  u16* qb  = (u16*)(ws + szXB + szWA + szWP);
  u16* kb  = (u16*)((char*)qb + szQ);
  u16* vb  = (u16*)((char*)kb + szQ);
  u16* yb  = xb;    // reuse x-slot: attn writes y after qkv GEMM consumed xb

  // 1) casts / transposes
  cast_f32_bf16_k<<<dim3((NM_*NC_/4 + 255)/256), dim3(256), 0, stream>>>(x, xb, NM_*NC_/4);
  transpose_cast_k<<<dim3(3*NC_/32, NC_/32), dim3(32,8), 0, stream>>>(wa, wat, NC_, 3*NC_);
  transpose_cast_k<<<dim3(NC_/32, NC_/32), dim3(32,8), 0, stream>>>(wp, wpt, NC_, NC_);
  // 2) qkv = x @ w_attn + b_attn  -> q*scale, k, v^T(permuted) scattered
  gemm128<0><<<dim3(3*NC_/128, NM_/128), dim3(256), 0, stream>>>(
      xb, wat, ba, qb, kb, vb, (float*)nullptr, NC_);
  // 3) flash attention -> y [B,T,C] bf16  (768 blocks x 4 independent waves)
  attn_kernel<<<dim3(NB_*NH_*(NT_/128)), dim3(256), 0, stream>>>(qb, kb, vb, yb);
  // 4) out = y @ w_proj + b_proj (f32)
  gemm128<1><<<dim3(NC_/128, NM_/128), dim3(256), 0, stream>>>(
      yb, wpt, bp, (u16*)nullptr, (u16*)nullptr, (u16*)nullptr, out, NC_);
}

// Round 5
// 169.263 us; speedup vs baseline: 1.4583x; 1.4583x over previous
//
#include <hip/hip_runtime.h>
#include <hip/hip_bf16.h>

typedef unsigned short u16;
typedef __attribute__((ext_vector_type(4))) short bf16x4;
typedef __attribute__((ext_vector_type(8))) short bf16x8;
typedef __attribute__((ext_vector_type(4))) float f32x4;
typedef __attribute__((ext_vector_type(16))) float f32x16;

#define NB_ 4
#define NT_ 2048
#define NC_ 768
#define NH_ 12
#define ND_ 64
#define NM_ (NB_*NT_)   // 8192 rows

// 1/sqrt(64) * log2(e): folded into q at the QKV epilogue -> attention runs in exp2 domain
#define SCQ_ 0.18033688011112042f

__device__ __forceinline__ u16 f2bf(float f){
  union { float f; unsigned u; } c; c.f = f;
  unsigned u = c.u;
  return (u16)((u + 0x7fffu + ((u>>16)&1u)) >> 16);  // RNE
}

__device__ __forceinline__ unsigned pkbf(float a, float b){
  __hip_bfloat162 h = __float22bfloat162_rn(make_float2(a,b));  // v_cvt_pk_bf16_f32
  union { __hip_bfloat162 h; unsigned u; } c; c.h = h; return c.u;
}

__device__ __forceinline__ bf16x8 cat4(bf16x4 lo, bf16x4 hi){
  return __builtin_shufflevector(lo, hi, 0,1,2,3,4,5,6,7);
}

__device__ __forceinline__ f32x4 mfma16(bf16x8 a, bf16x8 b, f32x4 c){
  return __builtin_amdgcn_mfma_f32_16x16x32_bf16(a, b, c, 0, 0, 0);
}
__device__ __forceinline__ f32x16 mfma32(bf16x8 a, bf16x8 b, f32x16 c){
  return __builtin_amdgcn_mfma_f32_32x32x16_bf16(a, b, c, 0, 0, 0);
}

__device__ __forceinline__ void gload_lds16(const void* g, void* l){
  __builtin_amdgcn_global_load_lds(
    (const __attribute__((address_space(1))) void*)g,
    (__attribute__((address_space(3))) void*)l, 16, 0, 0);
}

// ---------------- cast x (f32 -> bf16), 4 elems/thread ----------------
__global__ __launch_bounds__(256) void cast_f32_bf16_k(
    const float* __restrict__ in, u16* __restrict__ out, int n4){
  int i = blockIdx.x*256 + threadIdx.x;
  if (i >= n4) return;
  float4 v = ((const float4*)in)[i];
  bf16x4 o;
  o[0]=(short)f2bf(v.x); o[1]=(short)f2bf(v.y);
  o[2]=(short)f2bf(v.z); o[3]=(short)f2bf(v.w);
  ((bf16x4*)out)[i] = o;
}

// ------------- transpose + cast: in f32 [R][Cc] -> out bf16 [Cc][R] -------------
__global__ __launch_bounds__(256) void transpose_cast_k(
    const float* __restrict__ in, u16* __restrict__ out, int R, int Cc){
  __shared__ float tile[32][33];
  int tx = threadIdx.x, ty = threadIdx.y;          // 32 x 8
  int c0 = blockIdx.x*32, r0 = blockIdx.y*32;
  #pragma unroll
  for (int j=0;j<32;j+=8) tile[ty+j][tx] = in[(size_t)(r0+ty+j)*Cc + c0+tx];
  __syncthreads();
  #pragma unroll
  for (int j=0;j<32;j+=8) out[(size_t)(c0+ty+j)*R + r0+tx] = f2bf(tile[tx][ty+j]);
}

// ---------------- GEMM: C[128x128] = A[M,K] * BT[N,K]^T  (both bf16 row-major) -------
// MODE 0: qkv -> q*scale [B,H,T,D]; k,v in slot-major chunked layouts for the attn
//         kernel's linear LDS staging (see attn_kernel comments)
// MODE 1: proj -> f32 out [M][768] + bias
template<int MODE>
__global__ __launch_bounds__(256,2) void gemm128(
  const u16* __restrict__ A, const u16* __restrict__ BT, const float* __restrict__ bias,
  u16* __restrict__ qo, u16* __restrict__ ko, u16* __restrict__ vo,
  float* __restrict__ fo, int Ksz)
{
  __shared__ u16 lds[2][2][128*32];   // [buf][A/B][row*32], 64B rows, 32 KB total
  const int t = threadIdx.x, w = t>>6, l = t&63, g = l>>4, lr = l&15;
  const int brow = blockIdx.y*128, bcol = blockIdx.x*128;
  const int wr = (w>>1)*64, wc = (w&1)*64;

  f32x4 acc[4][4];
  #pragma unroll
  for (int i=0;i<4;i++)
    #pragma unroll
    for (int j=0;j<4;j++) acc[i][j] = (f32x4){0.f,0.f,0.f,0.f};

  auto stage = [&](int buf, int kt){
    #pragma unroll
    for (int it=0; it<2; ++it){
      int chunk = it*256 + t;           // 512 chunks per tile
      int r = chunk>>2;
      int sb = ((chunk&3)*16) ^ ((r&3)<<4);
      gload_lds16((const char*)(A  + (size_t)(brow+r)*Ksz + kt*32) + sb,
                  (char*)&lds[buf][0][0] + chunk*16);
      gload_lds16((const char*)(BT + (size_t)(bcol+r)*Ksz + kt*32) + sb,
                  (char*)&lds[buf][1][0] + chunk*16);
    }
  };

  auto ldfrag = [&](const u16* base, int row)->bf16x8{
    const char* rp = (const char*)(base + row*32);
    int sw = (row&3)<<4;
    bf16x4 lo = *(const bf16x4*)(rp + ((g*8) ^ sw));
    bf16x4 hi = *(const bf16x4*)(rp + ((32 + g*8) ^ sw));
    return cat4(lo,hi);
  };

  const int nk = Ksz/32;
  stage(0,0);
  __syncthreads();
  int cur = 0;
  for (int kt=0; kt<nk; ++kt){
    if (kt+1 < nk) stage(cur^1, kt+1);
    const u16* Ab = &lds[cur][0][0];
    const u16* Bb = &lds[cur][1][0];
    bf16x8 af[4], bfr[4];
    #pragma unroll
    for (int mi=0;mi<4;mi++) af[mi]  = ldfrag(Ab, wr + mi*16 + lr);
    #pragma unroll
    for (int nj=0;nj<4;nj++) bfr[nj] = ldfrag(Bb, wc + nj*16 + lr);
    #pragma unroll
    for (int mi=0;mi<4;mi++)
      #pragma unroll
      for (int nj=0;nj<4;nj++)
        acc[mi][nj] = mfma16(af[mi], bfr[nj], acc[mi][nj]);
    __syncthreads();
    cur ^= 1;
  }

  if (MODE == 1){
    #pragma unroll
    for (int nj=0;nj<4;nj++){
      int n = bcol + wc + nj*16 + lr;
      float bs = bias[n];
      #pragma unroll
      for (int mi=0;mi<4;mi++)
        #pragma unroll
        for (int r=0;r<4;r++){
          int m = brow + wr + mi*16 + g*4 + r;
          fo[(size_t)m*NC_ + n] = acc[mi][nj][r] + bs;
        }
    }
  } else {
    const int sec = bcol / NC_;                    // block-uniform (768 % 128 == 0)
    u16* outp = (sec==0) ? qo : (sec==1 ? ko : vo);
    #pragma unroll
    for (int nj=0;nj<4;nj++){
      int n = bcol + wc + nj*16 + lr;
      int cc = n - sec*NC_;
      int hd = cc >> 6, d = cc & 63;
      float bs = bias[n];
      #pragma unroll
      for (int mi=0;mi<4;mi++)
        #pragma unroll
        for (int r=0;r<4;r++){
          int m = brow + wr + mi*16 + g*4 + r;
          int bb = m >> 11, tt = m & 2047;
          float v = acc[mi][nj][r] + bs;
          if (sec == 0) v *= SCQ_;                 // pre-scale q for exp2-domain attn
          size_t base = ((size_t)bb*NH_ + hd)*((size_t)NT_*ND_);
          size_t off;
          if (sec == 0){
            off = base + (size_t)tt*ND_ + d;                   // q [B,H,T,D]
          } else if (sec == 1){
            // k slot-major: [chunk=tt>>6][slot=d>>3][row=tt&63][el=d&7]
            off = base + (size_t)(tt>>6)*4096 + (size_t)(d>>3)*512 + (tt&63)*8 + (d&7);
          } else {
            // v^T, kv-permuted within 16-blocks (p), then slot-major:
            // [chunk=p>>6][slot=(p&63)>>3][row=d][el=p&7]
            int p = (tt & ~15) | r | ((g&2)<<1) | ((g&1)<<3);
            off = base + (size_t)(p>>6)*4096 + (size_t)((p&63)>>3)*512 + d*8 + (p&7);
          }
          outp[off] = f2bf(v);
        }
    }
  }
}

// ---------------- flash attention v5: LDS slot-major staging, QBLK=128 ----------------
// 4 waves x 32 q share each K/V chunk (KVBLK=64, double-buffered 32 KB LDS).
// K/V stored slot-major per 64-kv chunk -> staging is a LINEAR tid*16B global_load_lds
// copy, and fragment ds_read_b128 is lane-contiguous (conflict-free, no swizzle).
// Swapped S^T = mfma(A=K, B=Q): softmax state lane-local (col=q=lane&31).
// pi-permuted K/Q slots (contraction-invariant); sigma-permuted V columns -> P feeds
// PV's B-operand in-lane (verified r4).
__global__ __launch_bounds__(256,4) void attn_kernel(
    const u16* __restrict__ qg, const u16* __restrict__ kg,
    const u16* __restrict__ vg, u16* __restrict__ y)
{
  __shared__ u16 lds[2][8192];    // [buf][ K 4096 el | V 4096 el ], 32 KB
  const int t = threadIdx.x, w = t>>6, l = t&63;
  const int lq = l&31, h = l>>5;
  const int bid = blockIdx.x;
  const int qt = 15 - (bid/48);   // heaviest q-tiles first
  const int bh = bid % 48;
  const int bb = bh / NH_, hh = bh % NH_;
  const u16* qp = qg + (size_t)bh*NT_*ND_;
  const u16* kp = kg + (size_t)bh*NT_*ND_;    // slot-major chunked
  const u16* vp = vg + (size_t)bh*ND_*NT_;    // slot-major chunked, kv-permuted
  const int qmin = qt*128 + w*32;
  const int q = qmin + lq;        // this lane's q row (column of S^T)

  // Q frags (pi-permuted): slot i of k-block ks holds Q[q][ks*16 + 8h + i]
  bf16x8 Qf[4];
  {
    const u16* qr = qp + (size_t)q*ND_ + 8*h;
    #pragma unroll
    for (int ks=0; ks<4; ++ks) Qf[ks] = *(const bf16x8*)(qr + ks*16);
  }

  f32x16 o0, o1;                  // O^T acc: col=q, row d=(r&3)+8*(r>>2)+4h (+32 o1)
  #pragma unroll
  for (int r=0;r<16;r++){ o0[r]=0.f; o1[r]=0.f; }
  float mrun = -3e38f, lsum = 0.f;
  const int nc = 2*qt + 2;        // same for all 4 waves (mask handles the tail)

  auto stage = [&](int buf, int c){
    const u16* kc = kp + c*4096;
    const u16* vc = vp + c*4096;
    #pragma unroll
    for (int it=0; it<2; ++it){
      gload_lds16(kc + (it*256 + t)*8, (char*)&lds[buf][0]    + (it*256 + t)*16);
      gload_lds16(vc + (it*256 + t)*8, (char*)&lds[buf][4096] + (it*256 + t)*16);
    }
  };

  stage(0,0);
  __syncthreads();
  int cur = 0;
  for (int c=0; c<nc; ++c){
    if (c+1 < nc) stage(cur^1, c+1);
    const u16* Kb = &lds[cur][0];
    const u16* Vb = &lds[cur][4096];
    const int kv0 = c*64;

    // S^T (64 kv x 32 q), q pre-scaled -> exp2 domain
    f32x16 s0, s1;
    #pragma unroll
    for (int r=0;r<16;r++){ s0[r]=0.f; s1[r]=0.f; }
    __builtin_amdgcn_s_setprio(1);
    #pragma unroll
    for (int ks=0; ks<4; ++ks){
      bf16x8 k0 = *(const bf16x8*)(Kb + ((2*ks+h)*64      + lq)*8);
      bf16x8 k1 = *(const bf16x8*)(Kb + ((2*ks+h)*64 + 32 + lq)*8);
      s0 = mfma32(k0, Qf[ks], s0);
      s1 = mfma32(k1, Qf[ks], s1);
    }
    __builtin_amdgcn_s_setprio(0);

    // causal mask: wave-uniform branch; covers diagonal and fully-masked chunks
    if (kv0 + 63 > qmin){
      #pragma unroll
      for (int r=0;r<16;r++){
        int kva = kv0 + (r&3) + 8*(r>>2) + 4*h;
        s0[r] = (kva      <= q) ? s0[r] : -3e38f;
        s1[r] = (kva + 32 <= q) ? s1[r] : -3e38f;
      }
    }

    // row max: pairwise tree (depth 5) + cross-half swap
    float mx[16];
    #pragma unroll
    for (int i=0;i<8;i++) mx[i]   = fmaxf(s0[2*i], s0[2*i+1]);
    #pragma unroll
    for (int i=0;i<8;i++) mx[8+i] = fmaxf(s1[2*i], s1[2*i+1]);
    #pragma unroll
    for (int st=8; st>=1; st>>=1)
      #pragma unroll
      for (int i=0;i<st;i++) mx[i] = fmaxf(mx[i], mx[i+st]);
    float m0 = fmaxf(mx[0], __shfl_xor(mx[0], 32));

    // defer-max (T13): rescale only when max grew past threshold
    if (__any(m0 > mrun + 8.f)){
      float mnew = fmaxf(mrun, m0);
      float fsc = exp2f(mrun - mnew);
      mrun = mnew;
      lsum *= fsc;
      #pragma unroll
      for (int r=0;r<16;r++){ o0[r]*=fsc; o1[r]*=fsc; }
    }

    // P = exp2(s - mrun); pack pairs; tree-sum partials
    float pp[16];
    union { unsigned wd[16]; bf16x8 v[4]; } pf;
    #pragma unroll
    for (int j=0;j<8;j++){
      float a = exp2f(s0[2*j] - mrun), b = exp2f(s0[2*j+1] - mrun);
      pp[j] = a + b;
      pf.wd[j] = pkbf(a,b);
    }
    #pragma unroll
    for (int j=0;j<8;j++){
      float a = exp2f(s1[2*j] - mrun), b = exp2f(s1[2*j+1] - mrun);
      pp[8+j] = a + b;
      pf.wd[8+j] = pkbf(a,b);
    }
    #pragma unroll
    for (int st=8; st>=1; st>>=1)
      #pragma unroll
      for (int i=0;i<st;i++) pp[i] += pp[i+st];
    lsum += pp[0] + __shfl_xor(pp[0], 32);

    // PV: O^T += V^T * P^T ; P regs feed B-operand directly (in-lane)
    __builtin_amdgcn_s_setprio(1);
    #pragma unroll
    for (int j=0;j<4;j++){
      bf16x8 v0 = *(const bf16x8*)(Vb + ((2*j+h)*64      + lq)*8);
      bf16x8 v1 = *(const bf16x8*)(Vb + ((2*j+h)*64 + 32 + lq)*8);
      o0 = mfma32(v0, pf.v[j], o0);
      o1 = mfma32(v1, pf.v[j], o1);
    }
    __builtin_amdgcn_s_setprio(0);
    __syncthreads();
    cur ^= 1;
  }

  // epilogue: y[b][t=q][hh*64+d] = O^T[d][q] / lsum  (8B packed stores)
  float inv = 1.f / lsum;
  u16* yr = y + ((size_t)bb*NT_ + q)*NC_ + hh*ND_;
  #pragma unroll
  for (int db=0; db<2; ++db){
    #pragma unroll
    for (int g2=0; g2<4; ++g2){
      float e0 = (db ? o1[g2*4+0] : o0[g2*4+0]) * inv;
      float e1 = (db ? o1[g2*4+1] : o0[g2*4+1]) * inv;
      float e2 = (db ? o1[g2*4+2] : o0[g2*4+2]) * inv;
      float e3 = (db ? o1[g2*4+3] : o0[g2*4+3]) * inv;
      unsigned w0 = pkbf(e0,e1), w1 = pkbf(e2,e3);
      int d0 = db*32 + g2*8 + 4*h;
      *(uint2*)(yr + d0) = make_uint2(w0, w1);
    }
  }
}

// ---------------- launch ----------------
extern "C" void kernel_launch(void* const* d_in, const int* in_sizes, int n_in,
                              void* d_out, int out_size, void* d_ws, size_t ws_size,
                              hipStream_t stream) {
  const float* x  = (const float*)d_in[0];
  const float* wa = (const float*)d_in[1];
  const float* ba = (const float*)d_in[2];
  const float* wp = (const float*)d_in[3];
  const float* bp = (const float*)d_in[4];
  float* out = (float*)d_out;

  char* ws = (char*)d_ws;
  const size_t szXB = (size_t)NM_*NC_*2;        // 12,582,912
  const size_t szWA = (size_t)3*NC_*NC_*2;      //  3,538,944
  const size_t szWP = (size_t)NC_*NC_*2;        //  1,179,648
  const size_t szQ  = szXB;
  u16* xb  = (u16*)(ws);
  u16* wat = (u16*)(ws + szXB);
  u16* wpt = (u16*)(ws + szXB + szWA);
  u16* qb  = (u16*)(ws + szXB + szWA + szWP);
  u16* kb  = (u16*)((char*)qb + szQ);
  u16* vb  = (u16*)((char*)kb + szQ);
  u16* yb  = xb;    // reuse x-slot: attn writes y after qkv GEMM consumed xb

  // 1) casts / transposes
  cast_f32_bf16_k<<<dim3((NM_*NC_/4 + 255)/256), dim3(256), 0, stream>>>(x, xb, NM_*NC_/4);
  transpose_cast_k<<<dim3(3*NC_/32, NC_/32), dim3(32,8), 0, stream>>>(wa, wat, NC_, 3*NC_);
  transpose_cast_k<<<dim3(NC_/32, NC_/32), dim3(32,8), 0, stream>>>(wp, wpt, NC_, NC_);
  // 2) qkv = x @ w_attn + b_attn  -> q*scale, k/v slot-major scattered
  gemm128<0><<<dim3(3*NC_/128, NM_/128), dim3(256), 0, stream>>>(
      xb, wat, ba, qb, kb, vb, (float*)nullptr, NC_);
  // 3) flash attention -> y [B,T,C] bf16  (768 blocks x 4 waves, QBLK=128)
  attn_kernel<<<dim3(NB_*NH_*(NT_/128)), dim3(256), 0, stream>>>(qb, kb, vb, yb);
  // 4) out = y @ w_proj + b_proj (f32)
  gemm128<1><<<dim3(NC_/128, NM_/128), dim3(256), 0, stream>>>(
      yb, wpt, bp, (u16*)nullptr, (u16*)nullptr, (u16*)nullptr, out, NC_);
}

// Round 6
// 147.296 us; speedup vs baseline: 1.6758x; 1.1491x over previous
//
#include <hip/hip_runtime.h>
#include <hip/hip_bf16.h>

typedef unsigned short u16;
typedef __attribute__((ext_vector_type(4))) short bf16x4;
typedef __attribute__((ext_vector_type(8))) short bf16x8;
typedef __attribute__((ext_vector_type(4))) float f32x4;
typedef __attribute__((ext_vector_type(16))) float f32x16;

#define NB_ 4
#define NT_ 2048
#define NC_ 768
#define NH_ 12
#define ND_ 64
#define NM_ (NB_*NT_)   // 8192 rows
#define KC_ 24          // K=768 -> 24 chunks of 32

// 1/sqrt(64) * log2(e): folded into q at the QKV epilogue -> attention runs in exp2 domain
#define SCQ_ 0.18033688011112042f

__device__ __forceinline__ u16 f2bf(float f){
  union { float f; unsigned u; } c; c.f = f;
  unsigned u = c.u;
  return (u16)((u + 0x7fffu + ((u>>16)&1u)) >> 16);  // RNE
}

__device__ __forceinline__ unsigned pkbf(float a, float b){
  __hip_bfloat162 h = __float22bfloat162_rn(make_float2(a,b));  // v_cvt_pk_bf16_f32
  union { __hip_bfloat162 h; unsigned u; } c; c.h = h; return c.u;
}

__device__ __forceinline__ f32x16 mfma32(bf16x8 a, bf16x8 b, f32x16 c){
  return __builtin_amdgcn_mfma_f32_32x32x16_bf16(a, b, c, 0, 0, 0);
}

__device__ __forceinline__ void gload_lds16(const void* g, void* l){
  __builtin_amdgcn_global_load_lds(
    (const __attribute__((address_space(1))) void*)g,
    (__attribute__((address_space(3))) void*)l, 16, 0, 0);
}

// A-blocked layout (for GEMM A operands, 128-row blocks):
//   off(row,k) = ((row>>7)*KC_ + (k>>5))*4096 + ((k>>3)&3)*1024 + (row&127)*8 + (k&7)
// B-blocked layout (for GEMM B operands, 256-row(n) blocks):
//   off(n,k)   = ((n>>8)*KC_ + (k>>5))*8192 + ((k>>3)&3)*2048 + (n&255)*8 + (k&7)

// ---------------- cast x (f32 -> bf16, A-blocked), 4 elems/thread ----------------
__global__ __launch_bounds__(256) void cast_f32_bf16_k(
    const float* __restrict__ in, u16* __restrict__ out, int n4){
  int i = blockIdx.x*256 + threadIdx.x;
  if (i >= n4) return;
  float4 v = ((const float4*)in)[i];
  int row = i / (NC_/4), k4 = (i % (NC_/4))*4;
  size_t off = (((size_t)(row>>7)*KC_ + (k4>>5))*4 + ((k4>>3)&3))*1024 + (row&127)*8 + (k4&7);
  bf16x4 o;
  o[0]=(short)f2bf(v.x); o[1]=(short)f2bf(v.y);
  o[2]=(short)f2bf(v.z); o[3]=(short)f2bf(v.w);
  *(bf16x4*)(out + off) = o;
}

// ------------- transpose + cast: in f32 [R=K][Cc=n] -> B-blocked bf16 -------------
__global__ __launch_bounds__(256) void transpose_cast_k(
    const float* __restrict__ in, u16* __restrict__ out, int R, int Cc){
  __shared__ float tile[32][33];
  int tx = threadIdx.x, ty = threadIdx.y;          // 32 x 8
  int c0 = blockIdx.x*32, r0 = blockIdx.y*32;
  #pragma unroll
  for (int j=0;j<32;j+=8) tile[ty+j][tx] = in[(size_t)(r0+ty+j)*Cc + c0+tx];
  __syncthreads();
  #pragma unroll
  for (int j=0;j<32;j+=8){
    int n = c0+ty+j, k = r0+tx;
    size_t off = (((size_t)(n>>8)*KC_ + (k>>5))*4 + ((k>>3)&3))*2048 + (n&255)*8 + (k&7);
    out[off] = f2bf(tile[tx][ty+j]);
  }
}

// ---------------- GEMM: 128x256 block, 4 waves x (128m x 64n), 32x32x16 MFMA -------
// A/B in blocked slot-major layouts -> linear gload_lds staging + conflict-free
// ds_read_b128 fragments (pi-permuted k on both operands, contraction-invariant).
// MODE 0: qkv -> q*scale [B,H,T,D]; k,v slot-major chunked for attn staging
// MODE 1: proj -> f32 out [M][768] + bias
template<int MODE>
__global__ __launch_bounds__(256,2) void gemm256(
  const u16* __restrict__ A, const u16* __restrict__ BT, const float* __restrict__ bias,
  u16* __restrict__ qo, u16* __restrict__ ko, u16* __restrict__ vo,
  float* __restrict__ fo)
{
  __shared__ u16 lds[2][4096 + 8192];   // [buf][ A 128x32 | B 256x32 ], 48 KB
  const int t = threadIdx.x, w = t>>6, l = t&63;
  const int lq = l&31, h = l>>5;
  const int NXB = (MODE==0) ? 9 : 3;
  const int nwg = 64*NXB;
  // bijective XCD swizzle (nwg % 8 == 0): each XCD gets a contiguous tile range
  int sw = (blockIdx.x & 7)*(nwg>>3) + (blockIdx.x >> 3);
  const int rb = sw / NXB, nb = sw % NXB;
  const int brow = rb*128, bcol = nb*256;
  const int wc = w*64;                   // wave n-base within block

  f32x16 acc[4][2];
  #pragma unroll
  for (int i=0;i<4;i++)
    #pragma unroll
    for (int j=0;j<2;j++)
      #pragma unroll
      for (int r=0;r<16;r++) acc[i][j][r] = 0.f;

  auto stage = [&](int buf, int kc){
    const u16* Ag = A  + ((size_t)(rb*KC_ + kc))*4096;
    const u16* Bg = BT + ((size_t)(nb*KC_ + kc))*8192;
    char* La = (char*)&lds[buf][0];
    char* Lb = (char*)&lds[buf][4096];
    #pragma unroll
    for (int it=0; it<2; ++it)
      gload_lds16(Ag + (it*256+t)*8, La + (it*256+t)*16);
    #pragma unroll
    for (int it=0; it<4; ++it)
      gload_lds16(Bg + (it*256+t)*8, Lb + (it*256+t)*16);
  };

  stage(0,0);
  __syncthreads();
  int cur = 0;
  for (int kc=0; kc<KC_; ++kc){
    if (kc+1 < KC_) stage(cur^1, kc+1);
    const u16* La = &lds[cur][0];
    const u16* Lb = &lds[cur][4096];
    #pragma unroll
    for (int ks=0; ks<2; ++ks){
      bf16x8 af[4], bfr[2];
      #pragma unroll
      for (int mi=0;mi<4;mi++)
        af[mi] = *(const bf16x8*)(La + ((2*ks+h)*128 + mi*32 + lq)*8);
      #pragma unroll
      for (int nj=0;nj<2;nj++)
        bfr[nj] = *(const bf16x8*)(Lb + ((2*ks+h)*256 + wc + nj*32 + lq)*8);
      __builtin_amdgcn_s_setprio(1);
      #pragma unroll
      for (int mi=0;mi<4;mi++)
        #pragma unroll
        for (int nj=0;nj<2;nj++)
          acc[mi][nj] = mfma32(af[mi], bfr[nj], acc[mi][nj]);
      __builtin_amdgcn_s_setprio(0);
    }
    __syncthreads();
    cur ^= 1;
  }

  // C/D map: col(n) = lq, row(m) offset = (r&3) + 8*(r>>2) + 4*h  (r in [0,16))
  if (MODE == 1){
    #pragma unroll
    for (int nj=0;nj<2;nj++){
      int n = bcol + wc + nj*32 + lq;
      float bs = bias[n];
      #pragma unroll
      for (int mi=0;mi<4;mi++)
        #pragma unroll
        for (int r=0;r<16;r++){
          int m = brow + mi*32 + (r&3) + 8*(r>>2) + 4*h;
          fo[(size_t)m*NC_ + n] = acc[mi][nj][r] + bs;
        }
    }
  } else {
    const int sec = nb/3;                  // 256-col blocks: 3 per q/k/v section
    u16* outp = (sec==0) ? qo : (sec==1 ? ko : vo);
    #pragma unroll
    for (int nj=0;nj<2;nj++){
      int n = bcol + wc + nj*32 + lq;
      int cc = n - sec*NC_;
      int hd = cc >> 6, d = cc & 63;
      float bs = bias[n];
      size_t base = ((size_t)0*NH_ + hd)*((size_t)NT_*ND_);  // bb added below
      #pragma unroll
      for (int mi=0;mi<4;mi++)
        #pragma unroll
        for (int r=0;r<16;r++){
          int m = brow + mi*32 + (r&3) + 8*(r>>2) + 4*h;
          int bb = m >> 11, tt = m & 2047;
          float v = acc[mi][nj][r] + bs;
          if (sec == 0) v *= SCQ_;         // pre-scale q for exp2-domain attn
          size_t bhbase = ((size_t)bb*NH_ + hd)*((size_t)NT_*ND_);
          size_t off;
          if (sec == 0){
            off = bhbase + (size_t)tt*ND_ + d;                 // q [B,H,T,D]
          } else if (sec == 1){
            // k slot-major: [chunk=tt>>6][slot=d>>3][row=tt&63][el=d&7]
            off = bhbase + (size_t)(tt>>6)*4096 + (size_t)(d>>3)*512 + (tt&63)*8 + (d&7);
          } else {
            // v^T, kv sigma-permuted within 16-blocks, slot-major over position p
            int p = (tt & ~15) | (h<<3) | (r&3) | (((r>>2)&1)<<2);
            off = bhbase + (size_t)(p>>6)*4096 + (size_t)((p&63)>>3)*512 + d*8 + (p&7);
          }
          outp[off] = f2bf(v);
          (void)base;
        }
    }
  }
}

// ---------------- flash attention v5: LDS slot-major staging, QBLK=128 ----------------
// (r5-verified) 4 waves x 32 q share each K/V chunk (KVBLK=64, dbuf 32 KB LDS).
// Epilogue now writes y in the A-blocked layout consumed by the proj GEMM.
__global__ __launch_bounds__(256,4) void attn_kernel(
    const u16* __restrict__ qg, const u16* __restrict__ kg,
    const u16* __restrict__ vg, u16* __restrict__ y)
{
  __shared__ u16 lds[2][8192];    // [buf][ K 4096 el | V 4096 el ], 32 KB
  const int t = threadIdx.x, w = t>>6, l = t&63;
  const int lq = l&31, h = l>>5;
  const int bid = blockIdx.x;
  const int qt = 15 - (bid/48);   // heaviest q-tiles first
  const int bh = bid % 48;
  const int bb = bh / NH_, hh = bh % NH_;
  const u16* qp = qg + (size_t)bh*NT_*ND_;
  const u16* kp = kg + (size_t)bh*NT_*ND_;    // slot-major chunked
  const u16* vp = vg + (size_t)bh*ND_*NT_;    // slot-major chunked, kv-permuted
  const int qmin = qt*128 + w*32;
  const int q = qmin + lq;        // this lane's q row (column of S^T)

  // Q frags (pi-permuted): slot i of k-block ks holds Q[q][ks*16 + 8h + i]
  bf16x8 Qf[4];
  {
    const u16* qr = qp + (size_t)q*ND_ + 8*h;
    #pragma unroll
    for (int ks=0; ks<4; ++ks) Qf[ks] = *(const bf16x8*)(qr + ks*16);
  }

  f32x16 o0, o1;                  // O^T acc: col=q, row d=(r&3)+8*(r>>2)+4h (+32 o1)
  #pragma unroll
  for (int r=0;r<16;r++){ o0[r]=0.f; o1[r]=0.f; }
  float mrun = -3e38f, lsum = 0.f;
  const int nc = 2*qt + 2;        // same for all 4 waves (mask handles the tail)

  auto stage = [&](int buf, int c){
    const u16* kc = kp + c*4096;
    const u16* vc = vp + c*4096;
    #pragma unroll
    for (int it=0; it<2; ++it){
      gload_lds16(kc + (it*256 + t)*8, (char*)&lds[buf][0]    + (it*256 + t)*16);
      gload_lds16(vc + (it*256 + t)*8, (char*)&lds[buf][4096] + (it*256 + t)*16);
    }
  };

  stage(0,0);
  __syncthreads();
  int cur = 0;
  for (int c=0; c<nc; ++c){
    if (c+1 < nc) stage(cur^1, c+1);
    const u16* Kb = &lds[cur][0];
    const u16* Vb = &lds[cur][4096];
    const int kv0 = c*64;

    // S^T (64 kv x 32 q), q pre-scaled -> exp2 domain
    f32x16 s0, s1;
    #pragma unroll
    for (int r=0;r<16;r++){ s0[r]=0.f; s1[r]=0.f; }
    __builtin_amdgcn_s_setprio(1);
    #pragma unroll
    for (int ks=0; ks<4; ++ks){
      bf16x8 k0 = *(const bf16x8*)(Kb + ((2*ks+h)*64      + lq)*8);
      bf16x8 k1 = *(const bf16x8*)(Kb + ((2*ks+h)*64 + 32 + lq)*8);
      s0 = mfma32(k0, Qf[ks], s0);
      s1 = mfma32(k1, Qf[ks], s1);
    }
    __builtin_amdgcn_s_setprio(0);

    // causal mask: wave-uniform branch; covers diagonal and fully-masked chunks
    if (kv0 + 63 > qmin){
      #pragma unroll
      for (int r=0;r<16;r++){
        int kva = kv0 + (r&3) + 8*(r>>2) + 4*h;
        s0[r] = (kva      <= q) ? s0[r] : -3e38f;
        s1[r] = (kva + 32 <= q) ? s1[r] : -3e38f;
      }
    }

    // row max: pairwise tree (depth 5) + cross-half swap
    float mx[16];
    #pragma unroll
    for (int i=0;i<8;i++) mx[i]   = fmaxf(s0[2*i], s0[2*i+1]);
    #pragma unroll
    for (int i=0;i<8;i++) mx[8+i] = fmaxf(s1[2*i], s1[2*i+1]);
    #pragma unroll
    for (int st=8; st>=1; st>>=1)
      #pragma unroll
      for (int i=0;i<st;i++) mx[i] = fmaxf(mx[i], mx[i+st]);
    float m0 = fmaxf(mx[0], __shfl_xor(mx[0], 32));

    // defer-max (T13): rescale only when max grew past threshold
    if (__any(m0 > mrun + 8.f)){
      float mnew = fmaxf(mrun, m0);
      float fsc = exp2f(mrun - mnew);
      mrun = mnew;
      lsum *= fsc;
      #pragma unroll
      for (int r=0;r<16;r++){ o0[r]*=fsc; o1[r]*=fsc; }
    }

    // P = exp2(s - mrun); pack pairs; tree-sum partials
    float pp[16];
    union { unsigned wd[16]; bf16x8 v[4]; } pf;
    #pragma unroll
    for (int j=0;j<8;j++){
      float a = exp2f(s0[2*j] - mrun), b = exp2f(s0[2*j+1] - mrun);
      pp[j] = a + b;
      pf.wd[j] = pkbf(a,b);
    }
    #pragma unroll
    for (int j=0;j<8;j++){
      float a = exp2f(s1[2*j] - mrun), b = exp2f(s1[2*j+1] - mrun);
      pp[8+j] = a + b;
      pf.wd[8+j] = pkbf(a,b);
    }
    #pragma unroll
    for (int st=8; st>=1; st>>=1)
      #pragma unroll
      for (int i=0;i<st;i++) pp[i] += pp[i+st];
    lsum += pp[0] + __shfl_xor(pp[0], 32);

    // PV: O^T += V^T * P^T ; P regs feed B-operand directly (in-lane)
    __builtin_amdgcn_s_setprio(1);
    #pragma unroll
    for (int j=0;j<4;j++){
      bf16x8 v0 = *(const bf16x8*)(Vb + ((2*j+h)*64      + lq)*8);
      bf16x8 v1 = *(const bf16x8*)(Vb + ((2*j+h)*64 + 32 + lq)*8);
      o0 = mfma32(v0, pf.v[j], o0);
      o1 = mfma32(v1, pf.v[j], o1);
    }
    __builtin_amdgcn_s_setprio(0);
    __syncthreads();
    cur ^= 1;
  }

  // epilogue: y in A-blocked layout for proj: row m = bb*NT+q, k = hh*64+d
  float inv = 1.f / lsum;
  const int m = bb*NT_ + q;
  const int rbm = m>>7, rr = m&127;
  #pragma unroll
  for (int db=0; db<2; ++db){
    #pragma unroll
    for (int g2=0; g2<4; ++g2){
      float e0 = (db ? o1[g2*4+0] : o0[g2*4+0]) * inv;
      float e1 = (db ? o1[g2*4+1] : o0[g2*4+1]) * inv;
      float e2 = (db ? o1[g2*4+2] : o0[g2*4+2]) * inv;
      float e3 = (db ? o1[g2*4+3] : o0[g2*4+3]) * inv;
      unsigned w0 = pkbf(e0,e1), w1 = pkbf(e2,e3);
      int k = hh*ND_ + db*32 + g2*8 + 4*h;
      size_t off = (((size_t)rbm*KC_ + (k>>5))*4 + ((k>>3)&3))*1024 + rr*8 + (k&7);
      *(uint2*)(y + off) = make_uint2(w0, w1);
    }
  }
}

// ---------------- launch ----------------
extern "C" void kernel_launch(void* const* d_in, const int* in_sizes, int n_in,
                              void* d_out, int out_size, void* d_ws, size_t ws_size,
                              hipStream_t stream) {
  const float* x  = (const float*)d_in[0];
  const float* wa = (const float*)d_in[1];
  const float* ba = (const float*)d_in[2];
  const float* wp = (const float*)d_in[3];
  const float* bp = (const float*)d_in[4];
  float* out = (float*)d_out;

  char* ws = (char*)d_ws;
  const size_t szXB = (size_t)NM_*NC_*2;        // 12,582,912
  const size_t szWA = (size_t)3*NC_*NC_*2;      //  3,538,944
  const size_t szWP = (size_t)NC_*NC_*2;        //  1,179,648
  const size_t szQ  = szXB;
  u16* xb  = (u16*)(ws);
  u16* wat = (u16*)(ws + szXB);
  u16* wpt = (u16*)(ws + szXB + szWA);
  u16* qb  = (u16*)(ws + szXB + szWA + szWP);
  u16* kb  = (u16*)((char*)qb + szQ);
  u16* vb  = (u16*)((char*)kb + szQ);
  u16* yb  = xb;    // reuse x-slot: attn writes y after qkv GEMM consumed xb

  // 1) casts / transposes into blocked layouts
  cast_f32_bf16_k<<<dim3((NM_*NC_/4 + 255)/256), dim3(256), 0, stream>>>(x, xb, NM_*NC_/4);
  transpose_cast_k<<<dim3(3*NC_/32, NC_/32), dim3(32,8), 0, stream>>>(wa, wat, NC_, 3*NC_);
  transpose_cast_k<<<dim3(NC_/32, NC_/32), dim3(32,8), 0, stream>>>(wp, wpt, NC_, NC_);
  // 2) qkv = x @ w_attn + b_attn  -> q*scale, k/v slot-major scattered
  gemm256<0><<<dim3(64*9), dim3(256), 0, stream>>>(xb, wat, ba, qb, kb, vb, (float*)nullptr);
  // 3) flash attention -> y (A-blocked) bf16
  attn_kernel<<<dim3(NB_*NH_*(NT_/128)), dim3(256), 0, stream>>>(qb, kb, vb, yb);
  // 4) out = y @ w_proj + b_proj (f32)
  gemm256<1><<<dim3(64*3), dim3(256), 0, stream>>>(yb, wpt, bp,
      (u16*)nullptr, (u16*)nullptr, (u16*)nullptr, out);
}